// Round 3
// baseline (757.382 us; speedup 1.0000x reference)
//
#include <hip/hip_runtime.h>
#include <hip/hip_bf16.h>

#define DEVI __device__ __forceinline__

using f32x4  = __attribute__((ext_vector_type(4))) float;
using s16x8  = __attribute__((ext_vector_type(8))) short;
using bf16x8 = __attribute__((ext_vector_type(8))) __bf16;

constexpr int kB = 8;     // batch
constexpr int kC = 256;   // channels
constexpr int kN = 4096;  // H*W
constexpr int kD = 16;    // qk dim

DEVI unsigned short f2bf(float f) {
  __hip_bfloat16 h = __float2bfloat16(f);
  return __builtin_bit_cast(unsigned short, h);
}
DEVI s16x8 ld16g(const unsigned short* p) { return *reinterpret_cast<const s16x8*>(p); }
DEVI s16x8 ld16l(const char* b, int off) { return *reinterpret_cast<const s16x8*>(b + off); }
DEVI void  st16l(char* b, int off, s16x8 v) { *reinterpret_cast<s16x8*>(b + off) = v; }
DEVI f32x4 mfma16(s16x8 a, s16x8 bb, f32x4 c) {
  // D = A_stored . B_stored^T ; D row <- A's lane&15 row, D col <- B's lane&15 row.
  return __builtin_amdgcn_mfma_f32_16x16x32_bf16(
      __builtin_bit_cast(bf16x8, a), __builtin_bit_cast(bf16x8, bb), c, 0, 0, 0);
}

// ---------- weights fp32 -> bf16 (row-major kept) ----------
__global__ __launch_bounds__(256) void k_cvt_w(
    const float* wq, const float* wk, const float* wv, const float* wo,
    unsigned short* wqb, unsigned short* wkb, unsigned short* wvb, unsigned short* wob) {
  int i = blockIdx.x * 256 + threadIdx.x;
  if (i < 4096)        wqb[i]         = f2bf(wq[i]);
  else if (i < 8192)   wkb[i - 4096]  = f2bf(wk[i - 4096]);
  else if (i < 73728)  wvb[i - 8192]  = f2bf(wv[i - 8192]);
  else if (i < 139264) wob[i - 73728] = f2bf(wo[i - 73728]);
}

// ---------- x [B][C][N] f32 -> xbT [B][N][C] bf16 (64x64 LDS transpose) ----------
// xbT is staged inside d_out (dead before the final kernel writes d_out).
__global__ __launch_bounds__(256) void k_xpose(const float* __restrict__ x,
                                               unsigned short* __restrict__ xbT) {
  __shared__ float tile[64][68];  // row stride 272B (16B-aligned float4 stores)
  int b = blockIdx.z, c0 = blockIdx.y * 64, n0 = blockIdx.x * 64;
  int t = threadIdx.x;
  const float* xp = x + ((size_t)b * kC + c0) * kN + n0;
#pragma unroll
  for (int i = 0; i < 4; i++) {
    int c_l = (t >> 4) + i * 16, n_l = (t & 15) * 4;
    float4 v = *reinterpret_cast<const float4*>(xp + (size_t)c_l * kN + n_l);
    *reinterpret_cast<float4*>(&tile[c_l][n_l]) = v;
  }
  __syncthreads();
  unsigned short* op = xbT + ((size_t)b * kN + n0) * kC + c0;
#pragma unroll
  for (int i = 0; i < 4; i++) {
    int n_l = (t >> 4) + i * 16, c_l = (t & 15) * 4;
    ushort4 u;
    u.x = f2bf(tile[c_l + 0][n_l]);
    u.y = f2bf(tile[c_l + 1][n_l]);
    u.z = f2bf(tile[c_l + 2][n_l]);
    u.w = f2bf(tile[c_l + 3][n_l]);
    *reinterpret_cast<ushort4*>(op + (size_t)n_l * kC + c_l) = u;
  }
}

// ---------- fused Q/K/V projection over one 64-row n-tile ----------
// q[b][n][16] = (Wq x + bq)*0.25 (D^-0.5 folded, exact pow2), k[b][n][16],
// Vt[b][e][n] = Wv x + bv  (pre-transposed for the attention kernel)
__global__ __launch_bounds__(256) void k_proj_qkv(
    const unsigned short* __restrict__ xbT,
    const unsigned short* __restrict__ wqb, const unsigned short* __restrict__ wkb,
    const unsigned short* __restrict__ wvb,
    const float* __restrict__ bq, const float* __restrict__ bk, const float* __restrict__ bv,
    unsigned short* __restrict__ qb, unsigned short* __restrict__ kb,
    unsigned short* __restrict__ vt) {
  __shared__ char xlds[64 * 512];  // [n_local][c] bf16, XOR-swizzled
  int b = blockIdx.y, n0 = blockIdx.x * 64;
  int t = threadIdx.x, lane = t & 63, w = t >> 6;
  int r = lane & 15, g = lane >> 4;
  const unsigned short* xp = xbT + ((size_t)b * kN + n0) * kC;
#pragma unroll
  for (int i = 0; i < 8; i++) {
    int ch = i * 256 + t;                 // 2048 16B chunks
    int n_l = ch >> 5, c8 = (ch & 31) << 3;
    s16x8 v = ld16g(xp + (size_t)n_l * kC + c8);
    int off = (n_l << 9) + (c8 << 1);
    off ^= (n_l & 7) << 4;
    st16l(xlds, off, v);
  }
  __syncthreads();
  // ---- Q and K: wave w computes rows n0 + w*16 .. +15 ----
  {
    f32x4 aq = {0.f, 0.f, 0.f, 0.f}, ak = {0.f, 0.f, 0.f, 0.f};
#pragma unroll
    for (int kt2 = 0; kt2 < 8; kt2++) {
      int arow = w * 16 + r;
      int off = (arow << 9) + ((kt2 * 32 + g * 8) << 1);
      off ^= (arow & 7) << 4;
      s16x8 a = ld16l(xlds, off);
      s16x8 bqf = ld16g(wqb + r * kC + kt2 * 32 + g * 8);
      s16x8 bkf = ld16g(wkb + r * kC + kt2 * 32 + g * 8);
      aq = mfma16(a, bqf, aq);
      ak = mfma16(a, bkf, ak);
    }
    int d = r;
    float bqd = bq[d], bkd = bk[d];
    unsigned short* qo = qb + ((size_t)b * kN + n0 + w * 16) * kD + d;
    unsigned short* ko = kb + ((size_t)b * kN + n0 + w * 16) * kD + d;
#pragma unroll
    for (int j = 0; j < 4; j++) {
      int row = g * 4 + j;
      qo[row * kD] = f2bf((aq[j] + bqd) * 0.25f);  // D^-0.5 folded into Q
      ko[row * kD] = f2bf(ak[j] + bkd);
    }
  }
  // ---- V: wave w computes e rows w*64 .. w*64+63, all 64 n cols ----
  {
    f32x4 acc[4][4];
#pragma unroll
    for (int p = 0; p < 4; p++)
#pragma unroll
      for (int np = 0; np < 4; np++) acc[p][np] = f32x4{0.f, 0.f, 0.f, 0.f};
#pragma unroll
    for (int kt2 = 0; kt2 < 8; kt2++) {
      s16x8 af[4], bf_[4];
#pragma unroll
      for (int p = 0; p < 4; p++) {
        int e = w * 64 + p * 16 + r;
        af[p] = ld16g(wvb + (size_t)e * kC + kt2 * 32 + g * 8);
      }
#pragma unroll
      for (int np = 0; np < 4; np++) {
        int nrow = np * 16 + r;
        int off = (nrow << 9) + ((kt2 * 32 + g * 8) << 1);
        off ^= (nrow & 7) << 4;
        bf_[np] = ld16l(xlds, off);
      }
#pragma unroll
      for (int p = 0; p < 4; p++)
#pragma unroll
        for (int np = 0; np < 4; np++) acc[p][np] = mfma16(af[p], bf_[np], acc[p][np]);
    }
#pragma unroll
    for (int p = 0; p < 4; p++) {
#pragma unroll
      for (int j = 0; j < 4; j++) {
        int e = w * 64 + p * 16 + g * 4 + j;
        float bve = bv[e];
        unsigned short* vo = vt + ((size_t)b * kC + e) * kN + n0;
#pragma unroll
        for (int np = 0; np < 4; np++) vo[np * 16 + r] = f2bf(acc[p][np][j] + bve);
      }
    }
  }
}

// ---------- flash attention + fused O-projection + residual epilogue ----------
// Block = 64 queries (4 waves x 16), key tiles of 64. Grid flattened to 512
// blocks; b = id&7 so each XCD (id%8 heuristic) serves ONE batch's K+V
// (2.13 MB < 4 MB L2/XCD). Tail: O-proj GEMM vs Wo reading the block's 64x256
// attention output from LDS (reuses the V-tile LDS), writes gamma*(.)+x.
__global__ __launch_bounds__(256) void k_attn(
    const unsigned short* __restrict__ qb, const unsigned short* __restrict__ kb,
    const unsigned short* __restrict__ vt, const unsigned short* __restrict__ wob,
    const float* __restrict__ bo, const float* __restrict__ gamma,
    const float* __restrict__ x, float* __restrict__ out) {
  __shared__ char smem[40960];
  char* vlds = smem;               // [256 e][64 key] bf16, swizzled (32 KiB); later alds
  char* plds = smem + 32768;       // per-wave P [16 q][64 key] bf16, swizzled (8 KiB)
  int b = blockIdx.x & 7, q0 = (blockIdx.x >> 3) * 64;
  int t = threadIdx.x, lane = t & 63, w = t >> 6;
  int r = lane & 15, g = lane >> 4;
  const s16x8 z8 = {0, 0, 0, 0, 0, 0, 0, 0};
  // Q fragment (K padded 16->32 with zeros in lane groups g>=2)
  s16x8 qf = z8;
  if (g < 2) qf = ld16g(qb + ((size_t)b * kN + q0 + w * 16 + r) * kD + g * 8);
  f32x4 accO[16];
#pragma unroll
  for (int i = 0; i < 16; i++) accO[i] = f32x4{0.f, 0.f, 0.f, 0.f};
  float m[4], l[4];
#pragma unroll
  for (int j = 0; j < 4; j++) { m[j] = -1e30f; l[j] = 0.f; }
  const unsigned short* vbase = vt + (size_t)b * kC * kN;
  const unsigned short* kbase = kb + (size_t)b * kN * kD;

  for (int kt = 0; kt < kN / 64; kt++) {
    int key0 = kt * 64;
    __syncthreads();
#pragma unroll
    for (int i = 0; i < 8; i++) {       // stage V tile [256 e][64 keys]
      int ch = i * 256 + t;
      int e = ch >> 3, kc = ch & 7;
      s16x8 v = ld16g(vbase + (size_t)e * kN + key0 + kc * 8);
      int off = (e << 7) + (kc << 4);
      off ^= (e & 7) << 4;
      st16l(vlds, off, v);
    }
    __syncthreads();

    // S = Q K^T (per wave: 16 q x 64 keys)
    f32x4 s[4];
#pragma unroll
    for (int nk = 0; nk < 4; nk++) {
      s16x8 kf = z8;
      if (g < 2) kf = ld16g(kbase + (size_t)(key0 + nk * 16 + r) * kD + g * 8);
      f32x4 z = {0.f, 0.f, 0.f, 0.f};
      s[nk] = mfma16(qf, kf, z);
    }
    // clip + online softmax (stats per lane for q = g*4+j, replicated over 16 key lanes)
    float fs[4];
#pragma unroll
    for (int j = 0; j < 4; j++) {
      float mx = -1e30f;
#pragma unroll
      for (int nk = 0; nk < 4; nk++) {
        float v = s[nk][j];
        v = fminf(50.f, fmaxf(-50.f, v));
        s[nk][j] = v;
        mx = fmaxf(mx, v);
      }
      mx = fmaxf(mx, __shfl_xor(mx, 1));
      mx = fmaxf(mx, __shfl_xor(mx, 2));
      mx = fmaxf(mx, __shfl_xor(mx, 4));
      mx = fmaxf(mx, __shfl_xor(mx, 8));
      float mn = fmaxf(m[j], mx);
      fs[j] = __expf(m[j] - mn);
      m[j] = mn;
      float sum = 0.f;
#pragma unroll
      for (int nk = 0; nk < 4; nk++) {
        float p = __expf(s[nk][j] - mn);
        s[nk][j] = p;
        sum += p;
      }
      sum += __shfl_xor(sum, 1);
      sum += __shfl_xor(sum, 2);
      sum += __shfl_xor(sum, 4);
      sum += __shfl_xor(sum, 8);
      l[j] = l[j] * fs[j] + sum;
    }
    // write P (bf16) to wave-private swizzled LDS [q][key]
#pragma unroll
    for (int nk = 0; nk < 4; nk++)
#pragma unroll
      for (int j = 0; j < 4; j++) {
        int qrow = g * 4 + j, key = nk * 16 + r;
        int off = (qrow << 7) + (key << 1);
        off ^= (qrow & 7) << 4;
        *reinterpret_cast<unsigned short*>(plds + w * 2048 + off) = f2bf(s[nk][j]);
      }
    // rescale O by exp(m_old - m_new): acc rows ARE the stat-owner lanes
#pragma unroll
    for (int ep = 0; ep < 16; ep++)
#pragma unroll
      for (int j = 0; j < 4; j++) accO[ep][j] *= fs[j];
    // O += P V  (A = P from plds, B = V from vlds)
    s16x8 pa[2];
#pragma unroll
    for (int h = 0; h < 2; h++) {
      int off = (r << 7) + h * 64 + g * 16;
      off ^= (r & 7) << 4;
      pa[h] = ld16l(plds + w * 2048, off);
    }
#pragma unroll
    for (int ep = 0; ep < 16; ep++) {
#pragma unroll
      for (int h = 0; h < 2; h++) {
        int e = ep * 16 + r;
        int off = (e << 7) + h * 64 + g * 16;
        off ^= (e & 7) << 4;
        s16x8 vb = ld16l(vlds, off);
        accO[ep] = mfma16(pa[h], vb, accO[ep]);
      }
    }
  }
  // ---- fused O projection ----
  float inv[4];
#pragma unroll
  for (int j = 0; j < 4; j++) inv[j] = 1.f / l[j];
  __syncthreads();                      // everyone done reading vlds
  char* alds = smem;                    // [64 q][256 e] bf16, swizzled (32 KiB)
#pragma unroll
  for (int ep = 0; ep < 16; ep++)
#pragma unroll
    for (int j = 0; j < 4; j++) {
      int qrow = w * 16 + g * 4 + j;    // block-local query row 0..63
      int e = ep * 16 + r;
      int off = (qrow << 9) + (e << 1);
      off ^= (qrow & 7) << 4;
      *reinterpret_cast<unsigned short*>(alds + off) = f2bf(accO[ep][j] * inv[j]);
    }
  __syncthreads();
  f32x4 acc2[4][4];
#pragma unroll
  for (int p = 0; p < 4; p++)
#pragma unroll
    for (int np = 0; np < 4; np++) acc2[p][np] = f32x4{0.f, 0.f, 0.f, 0.f};
#pragma unroll
  for (int kt2 = 0; kt2 < 8; kt2++) {
    s16x8 af[4], bf_[4];
#pragma unroll
    for (int p = 0; p < 4; p++) {
      int f = w * 64 + p * 16 + r;
      af[p] = ld16g(wob + (size_t)f * kC + kt2 * 32 + g * 8);
    }
#pragma unroll
    for (int np = 0; np < 4; np++) {
      int mrow = np * 16 + r;
      int off = (mrow << 9) + ((kt2 * 32 + g * 8) << 1);
      off ^= (mrow & 7) << 4;
      bf_[np] = ld16l(alds, off);
    }
#pragma unroll
    for (int p = 0; p < 4; p++)
#pragma unroll
      for (int np = 0; np < 4; np++) acc2[p][np] = mfma16(af[p], bf_[np], acc2[p][np]);
  }
  float gm = fminf(1.f, fmaxf(0.f, gamma[0]));
#pragma unroll
  for (int p = 0; p < 4; p++) {
#pragma unroll
    for (int j = 0; j < 4; j++) {
      int f = w * 64 + p * 16 + g * 4 + j;
      float bof = bo[f];
      const float* xr = x + ((size_t)b * kC + f) * kN + q0;
      float* orow = out + ((size_t)b * kC + f) * kN + q0;
#pragma unroll
      for (int np = 0; np < 4; np++) {
        int mi = np * 16 + r;
        orow[mi] = gm * (acc2[p][np][j] + bof) + xr[mi];
      }
    }
  }
}

extern "C" void kernel_launch(void* const* d_in, const int* in_sizes, int n_in,
                              void* d_out, int out_size, void* d_ws, size_t ws_size,
                              hipStream_t stream) {
  const float* x     = (const float*)d_in[0];
  const float* Wq    = (const float*)d_in[1];
  const float* bq    = (const float*)d_in[2];
  const float* Wk    = (const float*)d_in[3];
  const float* bk    = (const float*)d_in[4];
  const float* Wv    = (const float*)d_in[5];
  const float* bv    = (const float*)d_in[6];
  const float* Wo    = (const float*)d_in[7];
  const float* bo    = (const float*)d_in[8];
  const float* gamma = (const float*)d_in[9];
  float* out = (float*)d_out;

  // xbT (16 MB bf16) lives in d_out (32 MB): dead before out is written.
  unsigned short* xbT = (unsigned short*)d_out;

  // Workspace: ~16.75 MB
  char* ws = (char*)d_ws;
  unsigned short* vtb = (unsigned short*)ws; ws += (size_t)kB * kC * kN * 2;  // 16 MB
  unsigned short* qb  = (unsigned short*)ws; ws += (size_t)kB * kN * kD * 2;  // 256 KB
  unsigned short* kbp = (unsigned short*)ws; ws += (size_t)kB * kN * kD * 2;  // 256 KB
  unsigned short* wqb = (unsigned short*)ws; ws += kD * kC * 2;
  unsigned short* wkb = (unsigned short*)ws; ws += kD * kC * 2;
  unsigned short* wvb = (unsigned short*)ws; ws += kC * kC * 2;
  unsigned short* wob = (unsigned short*)ws; ws += kC * kC * 2;

  k_cvt_w<<<dim3(544), dim3(256), 0, stream>>>(Wq, Wk, Wv, Wo, wqb, wkb, wvb, wob);
  k_xpose<<<dim3(kN / 64, kC / 64, kB), dim3(256), 0, stream>>>(x, xbT);
  k_proj_qkv<<<dim3(kN / 64, kB), dim3(256), 0, stream>>>(xbT, wqb, wkb, wvb,
                                                          bq, bk, bv, qb, kbp, vtb);
  k_attn<<<dim3(kN / 64 * kB), dim3(256), 0, stream>>>(qb, kbp, vtb, wob,
                                                       bo, gamma, x, out);
}

// Round 4
// 429.823 us; speedup vs baseline: 1.7621x; 1.7621x over previous
//
#include <hip/hip_runtime.h>
#include <hip/hip_bf16.h>

#define DEVI __device__ __forceinline__

using f32x4  = __attribute__((ext_vector_type(4))) float;
using s16x8  = __attribute__((ext_vector_type(8))) short;
using bf16x8 = __attribute__((ext_vector_type(8))) __bf16;

constexpr int kB = 8;     // batch
constexpr int kC = 256;   // channels
constexpr int kN = 4096;  // H*W
constexpr int kD = 16;    // qk dim

DEVI unsigned short f2bf(float f) {
  __hip_bfloat16 h = __float2bfloat16(f);
  return __builtin_bit_cast(unsigned short, h);
}
DEVI s16x8 ld16g(const unsigned short* p) { return *reinterpret_cast<const s16x8*>(p); }
DEVI s16x8 ld16l(const char* b, int off) { return *reinterpret_cast<const s16x8*>(b + off); }
DEVI void  st16l(char* b, int off, s16x8 v) { *reinterpret_cast<s16x8*>(b + off) = v; }
DEVI f32x4 mfma16(s16x8 a, s16x8 bb, f32x4 c) {
  // D = A_stored . B_stored^T ; D row <- A's lane&15 row, D col <- B's lane&15 row.
  return __builtin_amdgcn_mfma_f32_16x16x32_bf16(
      __builtin_bit_cast(bf16x8, a), __builtin_bit_cast(bf16x8, bb), c, 0, 0, 0);
}
// async global->LDS, 16B per lane; LDS dest = wave-uniform base + lane*16 (linear)
DEVI void gload_lds16(const void* g, void* l) {
  __builtin_amdgcn_global_load_lds((const __attribute__((address_space(1))) void*)g,
                                   (__attribute__((address_space(3))) void*)l, 16, 0, 0);
}

// ---------- weights fp32 -> bf16 (row-major kept) ----------
__global__ __launch_bounds__(256) void k_cvt_w(
    const float* wq, const float* wk, const float* wv, const float* wo,
    unsigned short* wqb, unsigned short* wkb, unsigned short* wvb, unsigned short* wob) {
  int i = blockIdx.x * 256 + threadIdx.x;
  if (i < 4096)        wqb[i]         = f2bf(wq[i]);
  else if (i < 8192)   wkb[i - 4096]  = f2bf(wk[i - 4096]);
  else if (i < 73728)  wvb[i - 8192]  = f2bf(wv[i - 8192]);
  else if (i < 139264) wob[i - 73728] = f2bf(wo[i - 73728]);
}

// ---------- x [B][C][N] f32 -> xbT [B][N][C] bf16 (64x64 LDS transpose) ----------
// xbT is staged inside d_out (dead before the final kernel writes d_out).
__global__ __launch_bounds__(256) void k_xpose(const float* __restrict__ x,
                                               unsigned short* __restrict__ xbT) {
  __shared__ float tile[64][68];  // row stride 272B (16B-aligned float4 stores)
  int b = blockIdx.z, c0 = blockIdx.y * 64, n0 = blockIdx.x * 64;
  int t = threadIdx.x;
  const float* xp = x + ((size_t)b * kC + c0) * kN + n0;
#pragma unroll
  for (int i = 0; i < 4; i++) {
    int c_l = (t >> 4) + i * 16, n_l = (t & 15) * 4;
    float4 v = *reinterpret_cast<const float4*>(xp + (size_t)c_l * kN + n_l);
    *reinterpret_cast<float4*>(&tile[c_l][n_l]) = v;
  }
  __syncthreads();
  unsigned short* op = xbT + ((size_t)b * kN + n0) * kC + c0;
#pragma unroll
  for (int i = 0; i < 4; i++) {
    int n_l = (t >> 4) + i * 16, c_l = (t & 15) * 4;
    ushort4 u;
    u.x = f2bf(tile[c_l + 0][n_l]);
    u.y = f2bf(tile[c_l + 1][n_l]);
    u.z = f2bf(tile[c_l + 2][n_l]);
    u.w = f2bf(tile[c_l + 3][n_l]);
    *reinterpret_cast<ushort4*>(op + (size_t)n_l * kC + c_l) = u;
  }
}

// ---------- fused Q/K/V projection over one 64-row n-tile ----------
// q[b][n][16] = (Wq x + bq)*0.25 (D^-0.5 folded, exact pow2), k[b][n][16],
// Vt[b][e][n] = Wv x + bv  (pre-transposed for the attention kernel)
__global__ __launch_bounds__(256) void k_proj_qkv(
    const unsigned short* __restrict__ xbT,
    const unsigned short* __restrict__ wqb, const unsigned short* __restrict__ wkb,
    const unsigned short* __restrict__ wvb,
    const float* __restrict__ bq, const float* __restrict__ bk, const float* __restrict__ bv,
    unsigned short* __restrict__ qb, unsigned short* __restrict__ kb,
    unsigned short* __restrict__ vt) {
  __shared__ char xlds[64 * 512];  // [n_local][c] bf16, XOR-swizzled
  int b = blockIdx.y, n0 = blockIdx.x * 64;
  int t = threadIdx.x, lane = t & 63, w = t >> 6;
  int r = lane & 15, g = lane >> 4;
  const unsigned short* xp = xbT + ((size_t)b * kN + n0) * kC;
#pragma unroll
  for (int i = 0; i < 8; i++) {
    int ch = i * 256 + t;                 // 2048 16B chunks
    int n_l = ch >> 5, c8 = (ch & 31) << 3;
    s16x8 v = ld16g(xp + (size_t)n_l * kC + c8);
    int off = (n_l << 9) + (c8 << 1);
    off ^= (n_l & 7) << 4;
    st16l(xlds, off, v);
  }
  __syncthreads();
  // ---- Q and K: wave w computes rows n0 + w*16 .. +15 ----
  {
    f32x4 aq = {0.f, 0.f, 0.f, 0.f}, ak = {0.f, 0.f, 0.f, 0.f};
#pragma unroll
    for (int kt2 = 0; kt2 < 8; kt2++) {
      int arow = w * 16 + r;
      int off = (arow << 9) + ((kt2 * 32 + g * 8) << 1);
      off ^= (arow & 7) << 4;
      s16x8 a = ld16l(xlds, off);
      s16x8 bqf = ld16g(wqb + r * kC + kt2 * 32 + g * 8);
      s16x8 bkf = ld16g(wkb + r * kC + kt2 * 32 + g * 8);
      aq = mfma16(a, bqf, aq);
      ak = mfma16(a, bkf, ak);
    }
    int d = r;
    float bqd = bq[d], bkd = bk[d];
    unsigned short* qo = qb + ((size_t)b * kN + n0 + w * 16) * kD + d;
    unsigned short* ko = kb + ((size_t)b * kN + n0 + w * 16) * kD + d;
#pragma unroll
    for (int j = 0; j < 4; j++) {
      int row = g * 4 + j;
      qo[row * kD] = f2bf((aq[j] + bqd) * 0.25f);  // D^-0.5 folded into Q
      ko[row * kD] = f2bf(ak[j] + bkd);
    }
  }
  // ---- V: wave w computes e rows w*64 .. w*64+63, all 64 n cols ----
  {
    f32x4 acc[4][4];
#pragma unroll
    for (int p = 0; p < 4; p++)
#pragma unroll
      for (int np = 0; np < 4; np++) acc[p][np] = f32x4{0.f, 0.f, 0.f, 0.f};
#pragma unroll
    for (int kt2 = 0; kt2 < 8; kt2++) {
      s16x8 af[4], bf_[4];
#pragma unroll
      for (int p = 0; p < 4; p++) {
        int e = w * 64 + p * 16 + r;
        af[p] = ld16g(wvb + (size_t)e * kC + kt2 * 32 + g * 8);
      }
#pragma unroll
      for (int np = 0; np < 4; np++) {
        int nrow = np * 16 + r;
        int off = (nrow << 9) + ((kt2 * 32 + g * 8) << 1);
        off ^= (nrow & 7) << 4;
        bf_[np] = ld16l(xlds, off);
      }
#pragma unroll
      for (int p = 0; p < 4; p++)
#pragma unroll
        for (int np = 0; np < 4; np++) acc[p][np] = mfma16(af[p], bf_[np], acc[p][np]);
    }
#pragma unroll
    for (int p = 0; p < 4; p++) {
#pragma unroll
      for (int j = 0; j < 4; j++) {
        int e = w * 64 + p * 16 + g * 4 + j;
        float bve = bv[e];
        unsigned short* vo = vt + ((size_t)b * kC + e) * kN + n0;
#pragma unroll
        for (int np = 0; np < 4; np++) vo[np * 16 + r] = f2bf(acc[p][np][j] + bve);
      }
    }
  }
}

// ---------- flash attention + fused O-projection + residual epilogue ----------
// Block = 64 queries (4 waves x 16), key tiles of 64. b = id&7 -> one batch per
// XCD L2. V staged via global_load_lds (linear LDS dest, swizzle applied to the
// per-lane GLOBAL source), double-buffered, ONE barrier per tile: stage(t+1)
// overlaps compute(t); the vmcnt(0) drain sits in the next barrier.
__global__ __launch_bounds__(256) void k_attn(
    const unsigned short* __restrict__ qb, const unsigned short* __restrict__ kb,
    const unsigned short* __restrict__ vt, const unsigned short* __restrict__ wob,
    const float* __restrict__ bo, const float* __restrict__ gamma,
    const float* __restrict__ x, float* __restrict__ out) {
  __shared__ char smem[73728];
  // [0,32K): vbuf0  [32K,64K): vbuf1  [64K,72K): per-wave P (4 x 2KiB)
  char* plds = smem + 65536;
  int b = blockIdx.x & 7, q0 = (blockIdx.x >> 3) * 64;
  int t = threadIdx.x, lane = t & 63, w = t >> 6;
  int r = lane & 15, g = lane >> 4;
  const s16x8 z8 = {0, 0, 0, 0, 0, 0, 0, 0};
  // Q fragment (K padded 16->32 with zeros in lane groups g>=2)
  s16x8 qf = z8;
  if (g < 2) qf = ld16g(qb + ((size_t)b * kN + q0 + w * 16 + r) * kD + g * 8);
  f32x4 accO[16];
#pragma unroll
  for (int i = 0; i < 16; i++) accO[i] = f32x4{0.f, 0.f, 0.f, 0.f};
  float m[4], l[4];
#pragma unroll
  for (int j = 0; j < 4; j++) { m[j] = -1e30f; l[j] = 0.f; }
  const unsigned short* vbase = vt + (size_t)b * kC * kN;
  const unsigned short* kbase = kb + (size_t)b * kN * kD;

  // stage V tile [256 e][64 keys] for tile starting at key0 into buf (async DMA).
  // Linear LDS slot (e,kc) receives global key-group kc^(e&7): the read-side XOR
  // swizzle and this source permutation are the same involution.
  auto stage_v = [&](int key0, char* buf) {
#pragma unroll
    for (int i = 0; i < 8; i++) {
      int ch = (w * 8 + i) * 64 + lane;       // 16B chunk id, lane-contiguous
      int e = ch >> 3, kc = ch & 7;
      int kcs = kc ^ (e & 7);
      gload_lds16(vbase + (size_t)e * kN + key0 + kcs * 8, buf + (w * 8 + i) * 1024);
    }
  };

  // prologue: stage tile 0; prefetch K frags for tile 0
  stage_v(0, smem);
  s16x8 kf_cur[4] = {z8, z8, z8, z8};
  if (g < 2)
#pragma unroll
    for (int nk = 0; nk < 4; nk++)
      kf_cur[nk] = ld16g(kbase + (size_t)(nk * 16 + r) * kD + g * 8);

  for (int kt = 0; kt < kN / 64; kt++) {
    char* vbuf = smem + ((kt & 1) << 15);
    __syncthreads();  // drains vmcnt: tile kt staged; prev tile's readers done
    if (kt + 1 < kN / 64) stage_v((kt + 1) * 64, smem + (((kt + 1) & 1) << 15));
    // prefetch K fragments for tile kt+1 (register prefetch)
    s16x8 kf_nxt[4] = {z8, z8, z8, z8};
    if (kt + 1 < kN / 64 && g < 2)
#pragma unroll
      for (int nk = 0; nk < 4; nk++)
        kf_nxt[nk] = ld16g(kbase + (size_t)((kt + 1) * 64 + nk * 16 + r) * kD + g * 8);

    // S = Q K^T (per wave: 16 q x 64 keys)
    f32x4 s[4];
#pragma unroll
    for (int nk = 0; nk < 4; nk++) {
      f32x4 z = {0.f, 0.f, 0.f, 0.f};
      s[nk] = mfma16(qf, kf_cur[nk], z);
    }
    // clip + online softmax (stats per lane for q = g*4+j, replicated over 16 key lanes)
    float fs[4];
    bool need = false;
#pragma unroll
    for (int j = 0; j < 4; j++) {
      float mx = -1e30f;
#pragma unroll
      for (int nk = 0; nk < 4; nk++) {
        float v = s[nk][j];
        v = fminf(50.f, fmaxf(-50.f, v));
        s[nk][j] = v;
        mx = fmaxf(mx, v);
      }
      mx = fmaxf(mx, __shfl_xor(mx, 1));
      mx = fmaxf(mx, __shfl_xor(mx, 2));
      mx = fmaxf(mx, __shfl_xor(mx, 4));
      mx = fmaxf(mx, __shfl_xor(mx, 8));
      float mn = fmaxf(m[j], mx);
      fs[j] = __expf(m[j] - mn);
      need = need || (mn != m[j]);
      m[j] = mn;
      float sum = 0.f;
#pragma unroll
      for (int nk = 0; nk < 4; nk++) {
        float p = __expf(s[nk][j] - mn);
        s[nk][j] = p;
        sum += p;
      }
      sum += __shfl_xor(sum, 1);
      sum += __shfl_xor(sum, 2);
      sum += __shfl_xor(sum, 4);
      sum += __shfl_xor(sum, 8);
      l[j] = l[j] * fs[j] + sum;
    }
    // write P (bf16) to wave-private swizzled LDS [q][key]
#pragma unroll
    for (int nk = 0; nk < 4; nk++)
#pragma unroll
      for (int j = 0; j < 4; j++) {
        int qrow = g * 4 + j, key = nk * 16 + r;
        int off = (qrow << 7) + (key << 1);
        off ^= (qrow & 7) << 4;
        *reinterpret_cast<unsigned short*>(plds + w * 2048 + off) = f2bf(s[nk][j]);
      }
    // rescale O by exp(m_old - m_new); skip when no lane's max moved (common case)
    if (__any(need)) {
#pragma unroll
      for (int ep = 0; ep < 16; ep++)
#pragma unroll
        for (int j = 0; j < 4; j++) accO[ep][j] *= fs[j];
    }
    // O += P V  (A = P from plds, B = V from vbuf)
    s16x8 pa[2];
#pragma unroll
    for (int h = 0; h < 2; h++) {
      int off = (r << 7) + h * 64 + g * 16;
      off ^= (r & 7) << 4;
      pa[h] = ld16l(plds + w * 2048, off);
    }
#pragma unroll
    for (int ep = 0; ep < 16; ep++) {
#pragma unroll
      for (int h = 0; h < 2; h++) {
        int e = ep * 16 + r;
        int off = (e << 7) + h * 64 + g * 16;
        off ^= (e & 7) << 4;
        s16x8 vb = ld16l(vbuf, off);
        accO[ep] = mfma16(pa[h], vb, accO[ep]);
      }
    }
#pragma unroll
    for (int nk = 0; nk < 4; nk++) kf_cur[nk] = kf_nxt[nk];
  }
  // ---- fused O projection ----
  float inv[4];
#pragma unroll
  for (int j = 0; j < 4; j++) inv[j] = 1.f / l[j];
  __syncthreads();                      // everyone done reading V buffers
  char* alds = smem;                    // [64 q][256 e] bf16, swizzled (32 KiB)
#pragma unroll
  for (int ep = 0; ep < 16; ep++)
#pragma unroll
    for (int j = 0; j < 4; j++) {
      int qrow = w * 16 + g * 4 + j;    // block-local query row 0..63
      int e = ep * 16 + r;
      int off = (qrow << 9) + (e << 1);
      off ^= (qrow & 7) << 4;
      *reinterpret_cast<unsigned short*>(alds + off) = f2bf(accO[ep][j] * inv[j]);
    }
  __syncthreads();
  f32x4 acc2[4][4];
#pragma unroll
  for (int p = 0; p < 4; p++)
#pragma unroll
    for (int np = 0; np < 4; np++) acc2[p][np] = f32x4{0.f, 0.f, 0.f, 0.f};
#pragma unroll
  for (int kt2 = 0; kt2 < 8; kt2++) {
    s16x8 af[4], bf_[4];
#pragma unroll
    for (int p = 0; p < 4; p++) {
      int f = w * 64 + p * 16 + r;
      af[p] = ld16g(wob + (size_t)f * kC + kt2 * 32 + g * 8);
    }
#pragma unroll
    for (int np = 0; np < 4; np++) {
      int mrow = np * 16 + r;
      int off = (mrow << 9) + ((kt2 * 32 + g * 8) << 1);
      off ^= (mrow & 7) << 4;
      bf_[np] = ld16l(alds, off);
    }
#pragma unroll
    for (int p = 0; p < 4; p++)
#pragma unroll
      for (int np = 0; np < 4; np++) acc2[p][np] = mfma16(af[p], bf_[np], acc2[p][np]);
  }
  float gm = fminf(1.f, fmaxf(0.f, gamma[0]));
#pragma unroll
  for (int p = 0; p < 4; p++) {
#pragma unroll
    for (int j = 0; j < 4; j++) {
      int f = w * 64 + p * 16 + g * 4 + j;
      float bof = bo[f];
      const float* xr = x + ((size_t)b * kC + f) * kN + q0;
      float* orow = out + ((size_t)b * kC + f) * kN + q0;
#pragma unroll
      for (int np = 0; np < 4; np++) {
        int mi = np * 16 + r;
        orow[mi] = gm * (acc2[p][np][j] + bof) + xr[mi];
      }
    }
  }
}

extern "C" void kernel_launch(void* const* d_in, const int* in_sizes, int n_in,
                              void* d_out, int out_size, void* d_ws, size_t ws_size,
                              hipStream_t stream) {
  const float* x     = (const float*)d_in[0];
  const float* Wq    = (const float*)d_in[1];
  const float* bq    = (const float*)d_in[2];
  const float* Wk    = (const float*)d_in[3];
  const float* bk    = (const float*)d_in[4];
  const float* Wv    = (const float*)d_in[5];
  const float* bv    = (const float*)d_in[6];
  const float* Wo    = (const float*)d_in[7];
  const float* bo    = (const float*)d_in[8];
  const float* gamma = (const float*)d_in[9];
  float* out = (float*)d_out;

  // xbT (16 MB bf16) lives in d_out (32 MB): dead before out is written.
  unsigned short* xbT = (unsigned short*)d_out;

  // Workspace: ~16.75 MB
  char* ws = (char*)d_ws;
  unsigned short* vtb = (unsigned short*)ws; ws += (size_t)kB * kC * kN * 2;  // 16 MB
  unsigned short* qb  = (unsigned short*)ws; ws += (size_t)kB * kN * kD * 2;  // 256 KB
  unsigned short* kbp = (unsigned short*)ws; ws += (size_t)kB * kN * kD * 2;  // 256 KB
  unsigned short* wqb = (unsigned short*)ws; ws += kD * kC * 2;
  unsigned short* wkb = (unsigned short*)ws; ws += kD * kC * 2;
  unsigned short* wvb = (unsigned short*)ws; ws += kC * kC * 2;
  unsigned short* wob = (unsigned short*)ws; ws += kC * kC * 2;

  k_cvt_w<<<dim3(544), dim3(256), 0, stream>>>(Wq, Wk, Wv, Wo, wqb, wkb, wvb, wob);
  k_xpose<<<dim3(kN / 64, kC / 64, kB), dim3(256), 0, stream>>>(x, xbT);
  k_proj_qkv<<<dim3(kN / 64, kB), dim3(256), 0, stream>>>(xbT, wqb, wkb, wvb,
                                                          bq, bk, bv, qb, kbp, vtb);
  k_attn<<<dim3(kN / 64 * kB), dim3(256), 0, stream>>>(qb, kbp, vtb, wob,
                                                       bo, gamma, x, out);
}

// Round 6
// 253.921 us; speedup vs baseline: 2.9827x; 1.6927x over previous
//
#include <hip/hip_runtime.h>
#include <hip/hip_bf16.h>

#define DEVI __device__ __forceinline__

using f32x4  = __attribute__((ext_vector_type(4))) float;
using s16x8  = __attribute__((ext_vector_type(8))) short;
using bf16x8 = __attribute__((ext_vector_type(8))) __bf16;

constexpr int kB = 8;     // batch
constexpr int kC = 256;   // channels
constexpr int kN = 4096;  // H*W
constexpr int kD = 16;    // qk dim

DEVI unsigned short f2bf(float f) {
  __hip_bfloat16 h = __float2bfloat16(f);
  return __builtin_bit_cast(unsigned short, h);
}
DEVI s16x8 ld16g(const unsigned short* p) { return *reinterpret_cast<const s16x8*>(p); }
DEVI s16x8 ld16l(const char* b, int off) { return *reinterpret_cast<const s16x8*>(b + off); }
DEVI void  st16l(char* b, int off, s16x8 v) { *reinterpret_cast<s16x8*>(b + off) = v; }
DEVI f32x4 mfma16(s16x8 a, s16x8 bb, f32x4 c) {
  // D = A_stored . B_stored^T ; D row <- A's lane&15 row, D col <- B's lane&15 row.
  return __builtin_amdgcn_mfma_f32_16x16x32_bf16(
      __builtin_bit_cast(bf16x8, a), __builtin_bit_cast(bf16x8, bb), c, 0, 0, 0);
}
// async global->LDS, 16B per lane; LDS dest = wave-uniform base + lane*16 (linear)
DEVI void gload_lds16(const void* g, void* l) {
  __builtin_amdgcn_global_load_lds((const __attribute__((address_space(1))) void*)g,
                                   (__attribute__((address_space(3))) void*)l, 16, 0, 0);
}

// ---------- weights fp32 -> bf16 (row-major kept) ----------
__global__ __launch_bounds__(256) void k_cvt_w(
    const float* wq, const float* wk, const float* wv, const float* wo,
    unsigned short* wqb, unsigned short* wkb, unsigned short* wvb, unsigned short* wob) {
  int i = blockIdx.x * 256 + threadIdx.x;
  if (i < 4096)        wqb[i]         = f2bf(wq[i]);
  else if (i < 8192)   wkb[i - 4096]  = f2bf(wk[i - 4096]);
  else if (i < 73728)  wvb[i - 8192]  = f2bf(wv[i - 8192]);
  else if (i < 139264) wob[i - 73728] = f2bf(wo[i - 73728]);
}

// ---------- x [B][C][N] f32 -> xbT [B][N][C] bf16 (64x64 LDS transpose) ----------
// xbT is staged inside d_out (dead before the final kernel writes d_out).
__global__ __launch_bounds__(256) void k_xpose(const float* __restrict__ x,
                                               unsigned short* __restrict__ xbT) {
  __shared__ float tile[64][68];  // row stride 272B (16B-aligned float4 stores)
  int b = blockIdx.z, c0 = blockIdx.y * 64, n0 = blockIdx.x * 64;
  int t = threadIdx.x;
  const float* xp = x + ((size_t)b * kC + c0) * kN + n0;
#pragma unroll
  for (int i = 0; i < 4; i++) {
    int c_l = (t >> 4) + i * 16, n_l = (t & 15) * 4;
    float4 v = *reinterpret_cast<const float4*>(xp + (size_t)c_l * kN + n_l);
    *reinterpret_cast<float4*>(&tile[c_l][n_l]) = v;
  }
  __syncthreads();
  unsigned short* op = xbT + ((size_t)b * kN + n0) * kC + c0;
#pragma unroll
  for (int i = 0; i < 4; i++) {
    int n_l = (t >> 4) + i * 16, c_l = (t & 15) * 4;
    ushort4 u;
    u.x = f2bf(tile[c_l + 0][n_l]);
    u.y = f2bf(tile[c_l + 1][n_l]);
    u.z = f2bf(tile[c_l + 2][n_l]);
    u.w = f2bf(tile[c_l + 3][n_l]);
    *reinterpret_cast<ushort4*>(op + (size_t)n_l * kC + c_l) = u;
  }
}

// ---------- fused Q/K/V projection over one 64-row n-tile ----------
__global__ __launch_bounds__(256) void k_proj_qkv(
    const unsigned short* __restrict__ xbT,
    const unsigned short* __restrict__ wqb, const unsigned short* __restrict__ wkb,
    const unsigned short* __restrict__ wvb,
    const float* __restrict__ bq, const float* __restrict__ bk, const float* __restrict__ bv,
    unsigned short* __restrict__ qb, unsigned short* __restrict__ kb,
    unsigned short* __restrict__ vt) {
  __shared__ char xlds[64 * 512];  // [n_local][c] bf16, XOR-swizzled
  int b = blockIdx.y, n0 = blockIdx.x * 64;
  int t = threadIdx.x, lane = t & 63, w = t >> 6;
  int r = lane & 15, g = lane >> 4;
  const unsigned short* xp = xbT + ((size_t)b * kN + n0) * kC;
#pragma unroll
  for (int i = 0; i < 8; i++) {
    int ch = i * 256 + t;                 // 2048 16B chunks
    int n_l = ch >> 5, c8 = (ch & 31) << 3;
    s16x8 v = ld16g(xp + (size_t)n_l * kC + c8);
    int off = (n_l << 9) + (c8 << 1);
    off ^= (n_l & 7) << 4;
    st16l(xlds, off, v);
  }
  __syncthreads();
  // ---- Q and K: wave w computes rows n0 + w*16 .. +15 ----
  {
    f32x4 aq = {0.f, 0.f, 0.f, 0.f}, ak = {0.f, 0.f, 0.f, 0.f};
#pragma unroll
    for (int kt2 = 0; kt2 < 8; kt2++) {
      int arow = w * 16 + r;
      int off = (arow << 9) + ((kt2 * 32 + g * 8) << 1);
      off ^= (arow & 7) << 4;
      s16x8 a = ld16l(xlds, off);
      s16x8 bqf = ld16g(wqb + r * kC + kt2 * 32 + g * 8);
      s16x8 bkf = ld16g(wkb + r * kC + kt2 * 32 + g * 8);
      aq = mfma16(a, bqf, aq);
      ak = mfma16(a, bkf, ak);
    }
    int d = r;
    float bqd = bq[d], bkd = bk[d];
    unsigned short* qo = qb + ((size_t)b * kN + n0 + w * 16) * kD + d;
    unsigned short* ko = kb + ((size_t)b * kN + n0 + w * 16) * kD + d;
#pragma unroll
    for (int j = 0; j < 4; j++) {
      int row = g * 4 + j;
      qo[row * kD] = f2bf((aq[j] + bqd) * 0.25f);  // D^-0.5 folded into Q
      ko[row * kD] = f2bf(ak[j] + bkd);
    }
  }
  // ---- V: wave w computes e rows w*64 .. w*64+63, all 64 n cols ----
  {
    f32x4 acc[4][4];
#pragma unroll
    for (int p = 0; p < 4; p++)
#pragma unroll
      for (int np = 0; np < 4; np++) acc[p][np] = f32x4{0.f, 0.f, 0.f, 0.f};
#pragma unroll
    for (int kt2 = 0; kt2 < 8; kt2++) {
      s16x8 af[4], bf_[4];
#pragma unroll
      for (int p = 0; p < 4; p++) {
        int e = w * 64 + p * 16 + r;
        af[p] = ld16g(wvb + (size_t)e * kC + kt2 * 32 + g * 8);
      }
#pragma unroll
      for (int np = 0; np < 4; np++) {
        int nrow = np * 16 + r;
        int off = (nrow << 9) + ((kt2 * 32 + g * 8) << 1);
        off ^= (nrow & 7) << 4;
        bf_[np] = ld16l(xlds, off);
      }
#pragma unroll
      for (int p = 0; p < 4; p++)
#pragma unroll
        for (int np = 0; np < 4; np++) acc[p][np] = mfma16(af[p], bf_[np], acc[p][np]);
    }
#pragma unroll
    for (int p = 0; p < 4; p++) {
#pragma unroll
      for (int j = 0; j < 4; j++) {
        int e = w * 64 + p * 16 + g * 4 + j;
        float bve = bv[e];
        unsigned short* vo = vt + ((size_t)b * kC + e) * kN + n0;
#pragma unroll
        for (int np = 0; np < 4; np++) vo[np * 16 + r] = f2bf(acc[p][np][j] + bve);
      }
    }
  }
}

// ---------- flash attention (swapped-QK layout) + fused O-projection ----------
// S^T = mfma(K,Q): lane owns query q=lane&15 (stats fully lane-local; only the
// per-tile MAX needs 2 shfls; the sum reduction is deferred to the end).
// PV = mfma(V^T, P): accO rows = e, cols = q -> rescale stays lane-aligned.
__global__ __launch_bounds__(256) void k_attn(
    const unsigned short* __restrict__ qb, const unsigned short* __restrict__ kb,
    const unsigned short* __restrict__ vt, const unsigned short* __restrict__ wob,
    const float* __restrict__ bo, const float* __restrict__ gamma,
    const float* __restrict__ x, float* __restrict__ out) {
  __shared__ char smem[73728];
  // [0,32K): vbuf0  [32K,64K): vbuf1  [64K,72K): per-wave P (4 x 2KiB)
  char* plds = smem + 65536;
  int b = blockIdx.x & 7, q0 = (blockIdx.x >> 3) * 64;
  int t = threadIdx.x, lane = t & 63, w = t >> 6;
  int r = lane & 15, g = lane >> 4;
  const s16x8 z8 = {0, 0, 0, 0, 0, 0, 0, 0};
  // Q fragment (B-operand): row = q = lane&15; K-dim 16 padded to 32 (g>=2 zero)
  s16x8 qf = z8;
  if (g < 2) qf = ld16g(qb + ((size_t)b * kN + q0 + w * 16 + r) * kD + g * 8);
  f32x4 accO[16];   // accO[ep][j] = O^T[e=16ep+4g+j][q=r]
#pragma unroll
  for (int i = 0; i < 16; i++) accO[i] = f32x4{0.f, 0.f, 0.f, 0.f};
  float m = -1e30f, lsum = 0.f;  // per-lane (query r); lsum is per-g partial
  const unsigned short* vbase = vt + (size_t)b * kC * kN;
  const unsigned short* kbase = kb + (size_t)b * kN * kD;

  // hoisted per-lane element offsets for V staging (linear LDS dest; the XOR
  // swizzle is applied to the GLOBAL source: same involution as the read side)
  int voff[8];
#pragma unroll
  for (int i = 0; i < 8; i++) {
    int ch = (w * 8 + i) * 64 + lane;
    int e = ch >> 3, kc = ch & 7;
    voff[i] = e * kN + (kc ^ (e & 7)) * 8;
  }
  // hoisted K-fragment offsets (A-operand: row=key 16t+r, k-dim padded)
  int koff[4];
#pragma unroll
  for (int nk = 0; nk < 4; nk++) koff[nk] = (nk * 16 + r) * kD + g * 8;

  auto stage_v = [&](int key0, char* buf) {
#pragma unroll
    for (int i = 0; i < 8; i++)
      gload_lds16(vbase + voff[i] + key0, buf + (w * 8 + i) * 1024);
  };

  // prologue: stage tile 0; prefetch K frags for tile 0
  stage_v(0, smem);
  s16x8 kf_cur[4] = {z8, z8, z8, z8};
  if (g < 2)
#pragma unroll
    for (int nk = 0; nk < 4; nk++) kf_cur[nk] = ld16g(kbase + koff[nk]);

  for (int kt = 0; kt < kN / 64; kt++) {
    char* vbuf = smem + ((kt & 1) << 15);
    __syncthreads();  // drains vmcnt: tile kt staged; prev tile's readers done
    if (kt + 1 < kN / 64) stage_v((kt + 1) * 64, smem + (((kt + 1) & 1) << 15));
    s16x8 kf_nxt[4] = {z8, z8, z8, z8};
    if (kt + 1 < kN / 64 && g < 2)
#pragma unroll
      for (int nk = 0; nk < 4; nk++)
        kf_nxt[nk] = ld16g(kbase + (kt + 1) * 64 * kD + koff[nk]);

    // S^T = K Q^T: s[t][j] = score(key = 16t+4g+j, query = r)
    f32x4 s[4];
#pragma unroll
    for (int nk = 0; nk < 4; nk++) {
      f32x4 z = {0.f, 0.f, 0.f, 0.f};
      s[nk] = mfma16(kf_cur[nk], qf, z);
    }
    // clip + per-lane online softmax (2 shfls only: cross-g max)
#pragma unroll
    for (int nk = 0; nk < 4; nk++)
#pragma unroll
      for (int j = 0; j < 4; j++) s[nk][j] = fminf(50.f, fmaxf(-50.f, s[nk][j]));
    float mx0 = fmaxf(fmaxf(s[0][0], s[0][1]), fmaxf(s[0][2], s[0][3]));
    float mx1 = fmaxf(fmaxf(s[1][0], s[1][1]), fmaxf(s[1][2], s[1][3]));
    float mx2 = fmaxf(fmaxf(s[2][0], s[2][1]), fmaxf(s[2][2], s[2][3]));
    float mx3 = fmaxf(fmaxf(s[3][0], s[3][1]), fmaxf(s[3][2], s[3][3]));
    float mx = fmaxf(fmaxf(mx0, mx1), fmaxf(mx2, mx3));
    mx = fmaxf(mx, __shfl_xor(mx, 16));
    mx = fmaxf(mx, __shfl_xor(mx, 32));
    float mn = fmaxf(m, mx);
    float fs = __expf(m - mn);
    bool need = (mn != m);
    m = mn;
#pragma unroll
    for (int nk = 0; nk < 4; nk++)
#pragma unroll
      for (int j = 0; j < 4; j++) s[nk][j] = __expf(s[nk][j] - mn);
    float sm0 = (s[0][0] + s[0][1]) + (s[0][2] + s[0][3]);
    float sm1 = (s[1][0] + s[1][1]) + (s[1][2] + s[1][3]);
    float sm2 = (s[2][0] + s[2][1]) + (s[2][2] + s[2][3]);
    float sm3 = (s[3][0] + s[3][1]) + (s[3][2] + s[3][3]);
    lsum = lsum * fs + ((sm0 + sm1) + (sm2 + sm3));  // per-g partial
    // pack P -> plds [q][key] bf16 (4 x ds_write_b64, ~2-way banked)
#pragma unroll
    for (int nk = 0; nk < 4; nk++) {
      unsigned p01 = (unsigned)f2bf(s[nk][0]) | ((unsigned)f2bf(s[nk][1]) << 16);
      unsigned p23 = (unsigned)f2bf(s[nk][2]) | ((unsigned)f2bf(s[nk][3]) << 16);
      int off = (r << 7) + ((nk * 32 + g * 8) ^ ((r & 7) << 4));
      *reinterpret_cast<uint2*>(plds + w * 2048 + off) = make_uint2(p01, p23);
    }
    // rescale O by exp(m_old - m_new); skip when no lane's max moved
    if (__any(need)) {
#pragma unroll
      for (int ep = 0; ep < 16; ep++)
#pragma unroll
        for (int j = 0; j < 4; j++) accO[ep][j] *= fs;
    }
    // O^T += V^T P : A = V^T (rows e), B = P (rows q)
    s16x8 pa[2];
#pragma unroll
    for (int h = 0; h < 2; h++) {
      int off = (r << 7) + ((h * 64 + g * 16) ^ ((r & 7) << 4));
      pa[h] = ld16l(plds + w * 2048, off);
    }
    __builtin_amdgcn_s_setprio(1);
#pragma unroll
    for (int ep = 0; ep < 16; ep++) {
#pragma unroll
      for (int h = 0; h < 2; h++) {
        int e = ep * 16 + r;
        int off = (e << 7) + ((h * 64 + g * 16) ^ ((e & 7) << 4));
        s16x8 vb = ld16l(vbuf, off);
        accO[ep] = mfma16(vb, pa[h], accO[ep]);
      }
    }
    __builtin_amdgcn_s_setprio(0);
#pragma unroll
    for (int nk = 0; nk < 4; nk++) kf_cur[nk] = kf_nxt[nk];
  }
  // final l reduction across the 4 g-replicas, then normalize
  lsum += __shfl_xor(lsum, 16);
  lsum += __shfl_xor(lsum, 32);
  float inv = 1.f / lsum;
  // ---- fused O projection ----
  __syncthreads();                      // everyone done reading V buffers
  char* alds = smem;                    // [64 q][256 e] bf16, swizzled (32 KiB)
#pragma unroll
  for (int ep = 0; ep < 16; ep++)
#pragma unroll
    for (int j = 0; j < 4; j++) {
      int qrow = w * 16 + r;            // block-local query row
      int e = ep * 16 + g * 4 + j;
      int off = (qrow << 9) + ((e << 1) ^ ((qrow & 7) << 4));
      *reinterpret_cast<unsigned short*>(alds + off) = f2bf(accO[ep][j] * inv);
    }
  __syncthreads();
  f32x4 acc2[4][4];
#pragma unroll
  for (int p = 0; p < 4; p++)
#pragma unroll
    for (int np = 0; np < 4; np++) acc2[p][np] = f32x4{0.f, 0.f, 0.f, 0.f};
#pragma unroll
  for (int kt2 = 0; kt2 < 8; kt2++) {
    s16x8 af[4], bf_[4];
#pragma unroll
    for (int p = 0; p < 4; p++) {
      int f = w * 64 + p * 16 + r;
      af[p] = ld16g(wob + (size_t)f * kC + kt2 * 32 + g * 8);
    }
#pragma unroll
    for (int np = 0; np < 4; np++) {
      int mrow = np * 16 + r;
      int off = (mrow << 9) + (((kt2 * 32 + g * 8) << 1) ^ ((mrow & 7) << 4));
      bf_[np] = ld16l(alds, off);
    }
#pragma unroll
    for (int p = 0; p < 4; p++)
#pragma unroll
      for (int np = 0; np < 4; np++) acc2[p][np] = mfma16(af[p], bf_[np], acc2[p][np]);
  }
  float gm = fminf(1.f, fmaxf(0.f, gamma[0]));
#pragma unroll
  for (int p = 0; p < 4; p++) {
#pragma unroll
    for (int j = 0; j < 4; j++) {
      int f = w * 64 + p * 16 + g * 4 + j;
      float bof = bo[f];
      const float* xr = x + ((size_t)b * kC + f) * kN + q0;
      float* orow = out + ((size_t)b * kC + f) * kN + q0;
#pragma unroll
      for (int np = 0; np < 4; np++) {
        int mi = np * 16 + r;
        orow[mi] = gm * (acc2[p][np][j] + bof) + xr[mi];
      }
    }
  }
}

extern "C" void kernel_launch(void* const* d_in, const int* in_sizes, int n_in,
                              void* d_out, int out_size, void* d_ws, size_t ws_size,
                              hipStream_t stream) {
  const float* x     = (const float*)d_in[0];
  const float* Wq    = (const float*)d_in[1];
  const float* bq    = (const float*)d_in[2];
  const float* Wk    = (const float*)d_in[3];
  const float* bk    = (const float*)d_in[4];
  const float* Wv    = (const float*)d_in[5];
  const float* bv    = (const float*)d_in[6];
  const float* Wo    = (const float*)d_in[7];
  const float* bo    = (const float*)d_in[8];
  const float* gamma = (const float*)d_in[9];
  float* out = (float*)d_out;

  // xbT (16 MB bf16) lives in d_out (32 MB): dead before out is written.
  unsigned short* xbT = (unsigned short*)d_out;

  // Workspace: ~16.75 MB
  char* ws = (char*)d_ws;
  unsigned short* vtb = (unsigned short*)ws; ws += (size_t)kB * kC * kN * 2;  // 16 MB
  unsigned short* qb  = (unsigned short*)ws; ws += (size_t)kB * kN * kD * 2;  // 256 KB
  unsigned short* kbp = (unsigned short*)ws; ws += (size_t)kB * kN * kD * 2;  // 256 KB
  unsigned short* wqb = (unsigned short*)ws; ws += kD * kC * 2;
  unsigned short* wkb = (unsigned short*)ws; ws += kD * kC * 2;
  unsigned short* wvb = (unsigned short*)ws; ws += kC * kC * 2;
  unsigned short* wob = (unsigned short*)ws; ws += kC * kC * 2;

  k_cvt_w<<<dim3(544), dim3(256), 0, stream>>>(Wq, Wk, Wv, Wo, wqb, wkb, wvb, wob);
  k_xpose<<<dim3(kN / 64, kC / 64, kB), dim3(256), 0, stream>>>(x, xbT);
  k_proj_qkv<<<dim3(kN / 64, kB), dim3(256), 0, stream>>>(xbT, wqb, wkb, wvb,
                                                          bq, bk, bv, qb, kbp, vtb);
  k_attn<<<dim3(kN / 64 * kB), dim3(256), 0, stream>>>(qb, kbp, vtb, wob,
                                                       bo, gamma, x, out);
}

// Round 8
// 232.215 us; speedup vs baseline: 3.2616x; 1.0935x over previous
//
#include <hip/hip_runtime.h>
#include <hip/hip_bf16.h>

#define DEVI __device__ __forceinline__

using f32x4  = __attribute__((ext_vector_type(4))) float;
using s16x8  = __attribute__((ext_vector_type(8))) short;
using bf16x8 = __attribute__((ext_vector_type(8))) __bf16;

constexpr int kB = 8;     // batch
constexpr int kC = 256;   // channels
constexpr int kN = 4096;  // H*W
constexpr int kD = 16;    // qk dim

#if __has_builtin(__builtin_amdgcn_exp2f)
#define EXP2(x) __builtin_amdgcn_exp2f(x)
#else
#define EXP2(x) exp2f(x)
#endif

DEVI unsigned short f2bf(float f) {
  __hip_bfloat16 h = __float2bfloat16(f);
  return __builtin_bit_cast(unsigned short, h);
}
DEVI unsigned cvtpk(float lo, float hi) {  // bf16(lo) | bf16(hi)<<16 (RNE)
  unsigned r;
  asm("v_cvt_pk_bf16_f32 %0, %1, %2" : "=v"(r) : "v"(lo), "v"(hi));
  return r;
}
DEVI s16x8 ld16g(const unsigned short* p) { return *reinterpret_cast<const s16x8*>(p); }
DEVI s16x8 ld16l(const char* b, int off) { return *reinterpret_cast<const s16x8*>(b + off); }
DEVI void  st16l(char* b, int off, s16x8 v) { *reinterpret_cast<s16x8*>(b + off) = v; }
DEVI f32x4 mfma16(s16x8 a, s16x8 bb, f32x4 c) {
  // D = A_stored . B_stored^T ; D row <- A's lane&15 row, D col <- B's lane&15 row.
  return __builtin_amdgcn_mfma_f32_16x16x32_bf16(
      __builtin_bit_cast(bf16x8, a), __builtin_bit_cast(bf16x8, bb), c, 0, 0, 0);
}
// async global->LDS, 16B per lane; LDS dest = wave-uniform base + lane*16 (linear)
DEVI void gload_lds16(const void* g, void* l) {
  __builtin_amdgcn_global_load_lds((const __attribute__((address_space(1))) void*)g,
                                   (__attribute__((address_space(3))) void*)l, 16, 0, 0);
}

// ---------- weights fp32 -> bf16 (row-major kept) ----------
__global__ __launch_bounds__(256) void k_cvt_w(
    const float* wq, const float* wk, const float* wv, const float* wo,
    unsigned short* wqb, unsigned short* wkb, unsigned short* wvb, unsigned short* wob) {
  int i = blockIdx.x * 256 + threadIdx.x;
  if (i < 4096)        wqb[i]         = f2bf(wq[i]);
  else if (i < 8192)   wkb[i - 4096]  = f2bf(wk[i - 4096]);
  else if (i < 73728)  wvb[i - 8192]  = f2bf(wv[i - 8192]);
  else if (i < 139264) wob[i - 73728] = f2bf(wo[i - 73728]);
}

// ---------- x [B][C][N] f32 -> xbT [B][N][C] bf16 (64x64 LDS transpose) ----------
// xbT is staged inside d_out (dead before the final kernel writes d_out).
__global__ __launch_bounds__(256) void k_xpose(const float* __restrict__ x,
                                               unsigned short* __restrict__ xbT) {
  __shared__ float tile[64][68];  // row stride 272B (16B-aligned float4 stores)
  int b = blockIdx.z, c0 = blockIdx.y * 64, n0 = blockIdx.x * 64;
  int t = threadIdx.x;
  const float* xp = x + ((size_t)b * kC + c0) * kN + n0;
#pragma unroll
  for (int i = 0; i < 4; i++) {
    int c_l = (t >> 4) + i * 16, n_l = (t & 15) * 4;
    float4 v = *reinterpret_cast<const float4*>(xp + (size_t)c_l * kN + n_l);
    *reinterpret_cast<float4*>(&tile[c_l][n_l]) = v;
  }
  __syncthreads();
  unsigned short* op = xbT + ((size_t)b * kN + n0) * kC + c0;
#pragma unroll
  for (int i = 0; i < 4; i++) {
    int n_l = (t >> 4) + i * 16, c_l = (t & 15) * 4;
    ushort4 u;
    u.x = f2bf(tile[c_l + 0][n_l]);
    u.y = f2bf(tile[c_l + 1][n_l]);
    u.z = f2bf(tile[c_l + 2][n_l]);
    u.w = f2bf(tile[c_l + 3][n_l]);
    *reinterpret_cast<ushort4*>(op + (size_t)n_l * kC + c_l) = u;
  }
}

// ---------- fused Q/K/V projection over one 64-row n-tile ----------
// q = (Wq x + bq) * 0.25*log2(e)  (D^-0.5 and exp2-domain fold), k = Wk x + bk,
// Vt[b][e][n] = Wv x + bv  (pre-transposed for the attention kernel)
__global__ __launch_bounds__(256) void k_proj_qkv(
    const unsigned short* __restrict__ xbT,
    const unsigned short* __restrict__ wqb, const unsigned short* __restrict__ wkb,
    const unsigned short* __restrict__ wvb,
    const float* __restrict__ bq, const float* __restrict__ bk, const float* __restrict__ bv,
    unsigned short* __restrict__ qb, unsigned short* __restrict__ kb,
    unsigned short* __restrict__ vt) {
  __shared__ char xlds[64 * 512];  // [n_local][c] bf16, XOR-swizzled
  int b = blockIdx.y, n0 = blockIdx.x * 64;
  int t = threadIdx.x, lane = t & 63, w = t >> 6;
  int r = lane & 15, g = lane >> 4;
  const unsigned short* xp = xbT + ((size_t)b * kN + n0) * kC;
#pragma unroll
  for (int i = 0; i < 8; i++) {
    int ch = i * 256 + t;                 // 2048 16B chunks
    int n_l = ch >> 5, c8 = (ch & 31) << 3;
    s16x8 v = ld16g(xp + (size_t)n_l * kC + c8);
    int off = (n_l << 9) + (c8 << 1);
    off ^= (n_l & 7) << 4;
    st16l(xlds, off, v);
  }
  __syncthreads();
  // ---- Q and K: wave w computes rows n0 + w*16 .. +15 ----
  {
    f32x4 aq = {0.f, 0.f, 0.f, 0.f}, ak = {0.f, 0.f, 0.f, 0.f};
#pragma unroll
    for (int kt2 = 0; kt2 < 8; kt2++) {
      int arow = w * 16 + r;
      int off = (arow << 9) + ((kt2 * 32 + g * 8) << 1);
      off ^= (arow & 7) << 4;
      s16x8 a = ld16l(xlds, off);
      s16x8 bqf = ld16g(wqb + r * kC + kt2 * 32 + g * 8);
      s16x8 bkf = ld16g(wkb + r * kC + kt2 * 32 + g * 8);
      aq = mfma16(a, bqf, aq);
      ak = mfma16(a, bkf, ak);
    }
    int d = r;
    float bqd = bq[d], bkd = bk[d];
    unsigned short* qo = qb + ((size_t)b * kN + n0 + w * 16) * kD + d;
    unsigned short* ko = kb + ((size_t)b * kN + n0 + w * 16) * kD + d;
#pragma unroll
    for (int j = 0; j < 4; j++) {
      int row = g * 4 + j;
      // 0.25 (D^-0.5) * log2(e): S*log2e comes out of QK^T directly
      qo[row * kD] = f2bf((aq[j] + bqd) * 0.3606737602f);
      ko[row * kD] = f2bf(ak[j] + bkd);
    }
  }
  // ---- V: wave w computes e rows w*64 .. w*64+63, all 64 n cols ----
  {
    f32x4 acc[4][4];
#pragma unroll
    for (int p = 0; p < 4; p++)
#pragma unroll
      for (int np = 0; np < 4; np++) acc[p][np] = f32x4{0.f, 0.f, 0.f, 0.f};
#pragma unroll
    for (int kt2 = 0; kt2 < 8; kt2++) {
      s16x8 af[4], bf_[4];
#pragma unroll
      for (int p = 0; p < 4; p++) {
        int e = w * 64 + p * 16 + r;
        af[p] = ld16g(wvb + (size_t)e * kC + kt2 * 32 + g * 8);
      }
#pragma unroll
      for (int np = 0; np < 4; np++) {
        int nrow = np * 16 + r;
        int off = (nrow << 9) + ((kt2 * 32 + g * 8) << 1);
        off ^= (nrow & 7) << 4;
        bf_[np] = ld16l(xlds, off);
      }
#pragma unroll
      for (int p = 0; p < 4; p++)
#pragma unroll
        for (int np = 0; np < 4; np++) acc[p][np] = mfma16(af[p], bf_[np], acc[p][np]);
    }
#pragma unroll
    for (int p = 0; p < 4; p++) {
#pragma unroll
      for (int j = 0; j < 4; j++) {
        int e = w * 64 + p * 16 + g * 4 + j;
        float bve = bv[e];
        unsigned short* vo = vt + ((size_t)b * kC + e) * kN + n0;
#pragma unroll
        for (int np = 0; np < 4; np++) vo[np * 16 + r] = f2bf(acc[p][np][j] + bve);
      }
    }
  }
}

// ---------- flash attention v3 + fused O-projection ----------
// Swapped QK^T (lane owns query q=lane&15), FIXED-max softmax in exp2 domain
// (shift-invariant: M=12 cannot overflow even at the +-50 clip bound), and
// e-split cooperative PV: wave w owns e-rows [w*64,w*64+64) for ALL 64 queries,
// halving V LDS reads. Two barriers/tile; the mid barrier is raw s_barrier +
// lgkmcnt(0) only, so the V-DMA/K-prefetch (vmcnt) stay in flight all tile.
__global__ __launch_bounds__(256) void k_attn(
    const unsigned short* __restrict__ qb, const unsigned short* __restrict__ kb,
    const unsigned short* __restrict__ vt, const unsigned short* __restrict__ wob,
    const float* __restrict__ bo, const float* __restrict__ gamma,
    const float* __restrict__ x, float* __restrict__ out) {
  __shared__ char smem[73984];
  // [0,32K): vbuf0  [32K,64K): vbuf1  [64K,72K): P (4 waves x 2KiB)  [72K,+256): linv
  char* plds = smem + 65536;
  float* linv = reinterpret_cast<float*>(smem + 73728);
  int b = blockIdx.x & 7, q0 = (blockIdx.x >> 3) * 64;
  int t = threadIdx.x, lane = t & 63, w = t >> 6;
  int r = lane & 15, g = lane >> 4;
  const s16x8 z8 = {0, 0, 0, 0, 0, 0, 0, 0};
  constexpr int NT = kN / 64;
  constexpr float kM  = 17.3123405f;   // 12*log2(e): fixed softmax shift
  constexpr float kLo = -89.4470925f;  // (-50-12)*log2(e)
  constexpr float kHi = 54.8224115f;   // ( 50-12)*log2(e)

  // Q fragment (B-operand): row = q = lane&15; K-dim 16 padded to 32 (g>=2 zero)
  s16x8 qf = z8;
  if (g < 2) qf = ld16g(qb + ((size_t)b * kN + q0 + w * 16 + r) * kD + g * 8);
  f32x4 accO[4][4];   // accO[ef][qg][jj] = O^T[e=w*64+ef*16+g*4+jj][q=qg*16+r]
#pragma unroll
  for (int ef = 0; ef < 4; ef++)
#pragma unroll
    for (int qg = 0; qg < 4; qg++) accO[ef][qg] = f32x4{0.f, 0.f, 0.f, 0.f};
  float lsum = 0.f;  // per-lane partial (query w*16+r, this lane's g-replica keys)
  const unsigned short* vbase = vt + (size_t)b * kC * kN;
  const unsigned short* kbase = kb + (size_t)b * kN * kD;

  // hoisted per-lane offsets for V staging (linear LDS dest; XOR swizzle applied
  // to the GLOBAL source: same involution as the read side)
  int voff[8];
#pragma unroll
  for (int i = 0; i < 8; i++) {
    int ch = (w * 8 + i) * 64 + lane;
    int e = ch >> 3, kc = ch & 7;
    voff[i] = e * kN + (kc ^ (e & 7)) * 8;
  }
  int koff[4];
#pragma unroll
  for (int nk = 0; nk < 4; nk++) koff[nk] = (nk * 16 + r) * kD + g * 8;
  // hoisted phase-2 LDS read bases (imm offsets walk ef/qg at compile time)
  const int swz = (r & 7) << 4;
  const int vE0 = ((w * 64 + r) << 7) + ((g * 16) ^ swz);
  const int vE1 = ((w * 64 + r) << 7) + ((64 + g * 16) ^ swz);
  const int pa0 = (r << 7) + ((g * 16) ^ swz);
  const int pa1 = (r << 7) + ((64 + g * 16) ^ swz);

  auto stage_v = [&](int key0, char* buf) {
#pragma unroll
    for (int i = 0; i < 8; i++)
      gload_lds16(vbase + voff[i] + key0, buf + (w * 8 + i) * 1024);
  };

  // prologue: stage tile 0; prefetch K frags for tile 0
  stage_v(0, smem);
  s16x8 kf_cur[4] = {z8, z8, z8, z8};
  if (g < 2)
#pragma unroll
    for (int nk = 0; nk < 4; nk++) kf_cur[nk] = ld16g(kbase + koff[nk]);

  const f32x4 cini = {-kM, -kM, -kM, -kM};  // -M folded into MFMA C-init
  for (int kt = 0; kt < NT; kt++) {
    char* vbuf = smem + ((kt & 1) << 15);
    __syncthreads();  // B: V(kt) staged (vmcnt drained); prev tile's LDS readers done
    s16x8 kf_nxt[4] = {z8, z8, z8, z8};
    if (kt + 1 < NT) {
      stage_v((kt + 1) * 64, smem + (((kt + 1) & 1) << 15));
      if (g < 2)
#pragma unroll
        for (int nk = 0; nk < 4; nk++)
          kf_nxt[nk] = ld16g(kbase + (kt + 1) * 64 * kD + koff[nk]);
    }

    // ---- phase 1: S^T = K Q^T (+ -M), clamp, exp2, partial sum, pack P ----
    f32x4 s[4];
#pragma unroll
    for (int nk = 0; nk < 4; nk++) s[nk] = mfma16(kf_cur[nk], qf, cini);
#pragma unroll
    for (int nk = 0; nk < 4; nk++)
#pragma unroll
      for (int j = 0; j < 4; j++)
        s[nk][j] = EXP2(fminf(kHi, fmaxf(kLo, s[nk][j])));
    float sm0 = (s[0][0] + s[0][1]) + (s[0][2] + s[0][3]);
    float sm1 = (s[1][0] + s[1][1]) + (s[1][2] + s[1][3]);
    float sm2 = (s[2][0] + s[2][1]) + (s[2][2] + s[2][3]);
    float sm3 = (s[3][0] + s[3][1]) + (s[3][2] + s[3][3]);
    lsum += (sm0 + sm1) + (sm2 + sm3);
#pragma unroll
    for (int nk = 0; nk < 4; nk++) {
      uint2 pk;
      pk.x = cvtpk(s[nk][0], s[nk][1]);
      pk.y = cvtpk(s[nk][2], s[nk][3]);
      int off = (r << 7) + ((nk * 32 + g * 8) ^ swz);
      *reinterpret_cast<uint2*>(plds + w * 2048 + off) = pk;
    }
    // A: P visible to all waves; vmcnt intentionally NOT drained here
    asm volatile("s_waitcnt lgkmcnt(0)" ::: "memory");
    __builtin_amdgcn_s_barrier();

    // ---- phase 2: e-split PV. O^T[e-slice][all q] += V^T P ----
    s16x8 pa[4][2];
#pragma unroll
    for (int qg = 0; qg < 4; qg++) {
      pa[qg][0] = ld16l(plds, qg * 2048 + pa0);
      pa[qg][1] = ld16l(plds, qg * 2048 + pa1);
    }
    __builtin_amdgcn_s_setprio(1);
#pragma unroll
    for (int ef = 0; ef < 4; ef++) {
      s16x8 vb0 = ld16l(vbuf, vE0 + ef * 2048);
      s16x8 vb1 = ld16l(vbuf, vE1 + ef * 2048);
#pragma unroll
      for (int qg = 0; qg < 4; qg++) {
        accO[ef][qg] = mfma16(vb0, pa[qg][0], accO[ef][qg]);
        accO[ef][qg] = mfma16(vb1, pa[qg][1], accO[ef][qg]);
      }
    }
    __builtin_amdgcn_s_setprio(0);
#pragma unroll
    for (int nk = 0; nk < 4; nk++) kf_cur[nk] = kf_nxt[nk];
  }
  // ---- share 1/l across waves (each wave owns stats for queries w*16+r) ----
  lsum += __shfl_xor(lsum, 16);
  lsum += __shfl_xor(lsum, 32);
  float inv = 1.f / lsum;
  if (g == 0) linv[w * 16 + r] = inv;
  __syncthreads();
  float inv4[4];
#pragma unroll
  for (int qg = 0; qg < 4; qg++) inv4[qg] = linv[qg * 16 + r];
  // ---- fused O projection: alds[q][e] (reuses vbuf0) ----
  char* alds = smem;  // [64 q][256 e] bf16, swizzled (32 KiB)
#pragma unroll
  for (int ef = 0; ef < 4; ef++)
#pragma unroll
    for (int qg = 0; qg < 4; qg++) {
      uint2 pk;
      pk.x = cvtpk(accO[ef][qg][0] * inv4[qg], accO[ef][qg][1] * inv4[qg]);
      pk.y = cvtpk(accO[ef][qg][2] * inv4[qg], accO[ef][qg][3] * inv4[qg]);
      int qrow = qg * 16 + r;
      int off = (qrow << 9) + ((w * 128 + ef * 32 + g * 8) ^ ((r & 7) << 4));
      *reinterpret_cast<uint2*>(alds + off) = pk;
    }
  __syncthreads();
  f32x4 acc2[4][4];
#pragma unroll
  for (int p = 0; p < 4; p++)
#pragma unroll
    for (int np = 0; np < 4; np++) acc2[p][np] = f32x4{0.f, 0.f, 0.f, 0.f};
#pragma unroll
  for (int kt2 = 0; kt2 < 8; kt2++) {
    s16x8 af[4], bf_[4];
#pragma unroll
    for (int p = 0; p < 4; p++) {
      int f = w * 64 + p * 16 + r;
      af[p] = ld16g(wob + (size_t)f * kC + kt2 * 32 + g * 8);
    }
#pragma unroll
    for (int np = 0; np < 4; np++) {
      int mrow = np * 16 + r;
      int off = (mrow << 9) + (((kt2 * 32 + g * 8) << 1) ^ ((mrow & 7) << 4));
      bf_[np] = ld16l(alds, off);
    }
#pragma unroll
    for (int p = 0; p < 4; p++)
#pragma unroll
      for (int np = 0; np < 4; np++) acc2[p][np] = mfma16(af[p], bf_[np], acc2[p][np]);
  }
  float gm = fminf(1.f, fmaxf(0.f, gamma[0]));
#pragma unroll
  for (int p = 0; p < 4; p++) {
#pragma unroll
    for (int j = 0; j < 4; j++) {
      int f = w * 64 + p * 16 + g * 4 + j;
      float bof = bo[f];
      const float* xr = x + ((size_t)b * kC + f) * kN + q0;
      float* orow = out + ((size_t)b * kC + f) * kN + q0;
#pragma unroll
      for (int np = 0; np < 4; np++) {
        int mi = np * 16 + r;
        orow[mi] = gm * (acc2[p][np][j] + bof) + xr[mi];
      }
    }
  }
}

extern "C" void kernel_launch(void* const* d_in, const int* in_sizes, int n_in,
                              void* d_out, int out_size, void* d_ws, size_t ws_size,
                              hipStream_t stream) {
  const float* x     = (const float*)d_in[0];
  const float* Wq    = (const float*)d_in[1];
  const float* bq    = (const float*)d_in[2];
  const float* Wk    = (const float*)d_in[3];
  const float* bk    = (const float*)d_in[4];
  const float* Wv    = (const float*)d_in[5];
  const float* bv    = (const float*)d_in[6];
  const float* Wo    = (const float*)d_in[7];
  const float* bo    = (const float*)d_in[8];
  const float* gamma = (const float*)d_in[9];
  float* out = (float*)d_out;

  // xbT (16 MB bf16) lives in d_out (32 MB): dead before out is written.
  unsigned short* xbT = (unsigned short*)d_out;

  // Workspace: ~16.75 MB
  char* ws = (char*)d_ws;
  unsigned short* vtb = (unsigned short*)ws; ws += (size_t)kB * kC * kN * 2;  // 16 MB
  unsigned short* qb  = (unsigned short*)ws; ws += (size_t)kB * kN * kD * 2;  // 256 KB
  unsigned short* kbp = (unsigned short*)ws; ws += (size_t)kB * kN * kD * 2;  // 256 KB
  unsigned short* wqb = (unsigned short*)ws; ws += kD * kC * 2;
  unsigned short* wkb = (unsigned short*)ws; ws += kD * kC * 2;
  unsigned short* wvb = (unsigned short*)ws; ws += kC * kC * 2;
  unsigned short* wob = (unsigned short*)ws; ws += kC * kC * 2;

  k_cvt_w<<<dim3(544), dim3(256), 0, stream>>>(Wq, Wk, Wv, Wo, wqb, wkb, wvb, wob);
  k_xpose<<<dim3(kN / 64, kC / 64, kB), dim3(256), 0, stream>>>(x, xbT);
  k_proj_qkv<<<dim3(kN / 64, kB), dim3(256), 0, stream>>>(xbT, wqb, wkb, wvb,
                                                          bq, bk, bv, qb, kbp, vtb);
  k_attn<<<dim3(kN / 64 * kB), dim3(256), 0, stream>>>(qb, kbp, vtb, wob,
                                                       bo, gamma, x, out);
}